// Round 7
// baseline (87.278 us; speedup 1.0000x reference)
//
#include <hip/hip_runtime.h>

#define N_ 4096
#define K_ 64
#define E_ (N_*K_)
#define H_ 256
#define EPS_ 1e-5f
#define L2E_ 1.4426950408889634f   // log2(e)
#define TL2E_ 2.8853900817779268f  // 2*log2(e)

#if __has_builtin(__builtin_amdgcn_exp2f)
#define EXP2(x) __builtin_amdgcn_exp2f(x)
#else
#define EXP2(x) __expf((x) * 0.6931471805599453f)
#endif

// tanh(x) = 1 - 2/(2^(2*log2e*x)+1); inf-safe (exp2(+inf)->inf, rcp(inf)=0)
__device__ __forceinline__ float ftanh(float x) {
    float e = EXP2(x * TL2E_);
    return 1.0f - 2.0f * __builtin_amdgcn_rcpf(e + 1.0f);
}

// One block: W01g[5*256] = TL2E * {W0@W1 (4 rows); b0@W1 + b1}, no atomics,
// no pre-zero. Also swp[0] = sum(W2) + b2 (independent of stats).
__global__ __launch_bounds__(256) void prep_kernel(
    const float* __restrict__ W0, const float* __restrict__ b0,
    const float* __restrict__ W1, const float* __restrict__ b1,
    const float* __restrict__ W2, const float* __restrict__ b2,
    float* __restrict__ W01g, float* __restrict__ swp)
{
    int c = threadIdx.x;
    float a0 = 0.f, a1 = 0.f, a2 = 0.f, a3 = 0.f, ab = 0.f;
    for (int h = 0; h < H_; ++h) {
        float w = W1[h * H_ + c];
        a0 = fmaf(W0[h], w, a0);
        a1 = fmaf(W0[H_ + h], w, a1);
        a2 = fmaf(W0[2 * H_ + h], w, a2);
        a3 = fmaf(W0[3 * H_ + h], w, a3);
        ab = fmaf(b0[h], w, ab);
    }
    W01g[c]          = TL2E_ * a0;
    W01g[H_ + c]     = TL2E_ * a1;
    W01g[2 * H_ + c] = TL2E_ * a2;
    W01g[3 * H_ + c] = TL2E_ * a3;
    W01g[4 * H_ + c] = TL2E_ * (ab + b1[c]);

    __shared__ float red[256];
    red[c] = W2[c];
    __syncthreads();
    for (int s = 128; s > 0; s >>= 1) {
        if (c < s) red[c] += red[c + s];
        __syncthreads();
    }
    if (c == 0) swp[0] = red[0] + b2[0];
}

// Per-column partial sums of r = 1/(2^u+1) and r^2 over a 128-edge tile.
// Weights already TL2E-prescaled. Coalesced part[block][512] writes, no atomics.
__global__ __launch_bounds__(256, 8) void stats_kernel(
    const float* __restrict__ coor, const float* __restrict__ W01g,
    float* __restrict__ part)
{
    const int c = threadIdx.x;
    const float w0 = W01g[c],          w1 = W01g[H_ + c];
    const float w2 = W01g[2 * H_ + c], w3 = W01g[3 * H_ + c];
    const float bb = W01g[4 * H_ + c];
    __shared__ float4 T[128];
    const int e0 = blockIdx.x * 128;
    if (c < 128) {
        float4 v = reinterpret_cast<const float4*>(coor)[e0 + c];
        T[c] = make_float4(ftanh(v.x), ftanh(v.y), ftanh(v.z), ftanh(v.w));
    }
    __syncthreads();
    float sr = 0.f, sr2 = 0.f;
    #pragma unroll 8
    for (int i = 0; i < 128; ++i) {
        float4 t = T[i];
        float u = fmaf(t.w, w3, fmaf(t.z, w2, fmaf(t.y, w1, fmaf(t.x, w0, bb))));
        float r = __builtin_amdgcn_rcpf(EXP2(u) + 1.0f);
        sr += r;
        sr2 = fmaf(r, r, sr2);
    }
    part[blockIdx.x * 512 + c] = sr;
    part[blockIdx.x * 512 + 256 + c] = sr2;
}

// Block j reduces part[:, j] and part[:, 256+j] over 2048 blocks, then thread 0
// BN-folds column j and writes its folded record (fuses old reduce+finalize).
__global__ __launch_bounds__(256) void reduce_fold_kernel(
    const float* __restrict__ part, const float* __restrict__ W01g,
    const float* __restrict__ gamma, const float* __restrict__ beta,
    const float* __restrict__ W2, float* __restrict__ folded)
{
    const int t = threadIdx.x;
    const int j = blockIdx.x;
    float s1 = 0.f, s2 = 0.f;
    #pragma unroll
    for (int k = 0; k < 8; ++k) {
        int b = t + 256 * k;
        s1 += part[(size_t)b * 512 + j];
        s2 += part[(size_t)b * 512 + 256 + j];
    }
    __shared__ float2 RED[256];
    RED[t] = make_float2(s1, s2);
    __syncthreads();
    for (int s = 128; s > 0; s >>= 1) {
        if (t < s) {
            RED[t].x += RED[t + s].x;
            RED[t].y += RED[t + s].y;
        }
        __syncthreads();
    }
    if (t == 0) {
        const float inv = 1.0f / (float)E_;
        float sp = RED[0].x * inv;
        float sq = RED[0].y * inv;
        float mu = 1.0f - 2.0f * sp;            // mean of h = 1-2r
        float var = 4.0f * fmaf(-sp, sp, sq);
        float a  = gamma[j] * rsqrtf(var + EPS_);
        float bf = fmaf(-mu, a, beta[j]);
        folded[8 * j + 0] = W01g[j];
        folded[8 * j + 1] = W01g[H_ + j];
        folded[8 * j + 2] = W01g[2 * H_ + j];
        folded[8 * j + 3] = W01g[3 * H_ + j];
        folded[8 * j + 4] = W01g[4 * H_ + j];
        folded[8 * j + 5] = -4.0f * L2E_ * a;   // coeff of r
        folded[8 * j + 6] = TL2E_ * (a + bf);   // const term
        folded[8 * j + 7] = -2.0f * W2[j];      // acc coeff on r2
    }
}

// Fused edge kernel (R5 structure, measured 44.5us / 32 VGPR / 8 blocks/CU).
// Block = 2 rows (128 edges): stage folded+tanh, zero-fill 2 out rows,
// thread = 4 edges x 32 cols, then waves 0,1 dedup + write.
__global__ __launch_bounds__(256, 8) void edge_kernel(
    const float* __restrict__ coor, const int* __restrict__ idx,
    const float* __restrict__ folded, const float* __restrict__ swp,
    const float* __restrict__ Wq, const float* __restrict__ bq,
    const float* __restrict__ Wk, const float* __restrict__ bk,
    const float* __restrict__ geo, const float* __restrict__ ang,
    float* __restrict__ out)
{
    __shared__ float4 FS[2 * H_];   // folded: col c -> FS[2c], FS[2c+1]
    __shared__ float4 TS[128];      // per-edge tanh quads
    __shared__ float2 EXY[128];     // per-edge (ex,ey)
    __shared__ float  ACC[8][128];  // chunk x edge partial accs

    const int t = threadIdx.x;
    const int row0 = blockIdx.x * 2;
    {
        const float4* F = reinterpret_cast<const float4*>(folded);
        FS[t] = F[t];
        FS[t + 256] = F[t + 256];
    }
    if (t < 128) {
        float4 ce = reinterpret_cast<const float4*>(coor)[row0 * K_ + t];
        TS[t] = make_float4(ftanh(ce.x), ftanh(ce.y), ftanh(ce.z), ftanh(ce.w));
        EXY[t] = make_float2(ce.x + ce.z, ce.y + ce.w);
    }
    {   // zero-fill this block's 2 rows (replaces 64MB memset)
        float4 z = make_float4(0.f, 0.f, 0.f, 0.f);
        float4* orow = reinterpret_cast<float4*>(out + (size_t)row0 * N_);
        #pragma unroll
        for (int i = 0; i < 8; ++i) orow[i * 256 + t] = z;
    }
    __syncthreads();   // FS/TS ready; zero stores drained (vmcnt before barrier)

    // ---- compute: 4 edges x 32 columns per thread ----
    const int eg = (t & 31) * 4;
    const int chunk = t >> 5;
    const float4 tq0 = TS[eg], tq1 = TS[eg + 1], tq2 = TS[eg + 2], tq3 = TS[eg + 3];
    const float4* Fp = &FS[chunk * 64];
    float a0 = 0.f, a1 = 0.f, a2 = 0.f, a3 = 0.f;
    #pragma unroll 4
    for (int i = 0; i < 32; ++i) {
        float4 f0 = Fp[2 * i];
        float4 f1 = Fp[2 * i + 1];
        #define EVAL(tq, ak) { \
            float u = fmaf(tq.w, f0.w, fmaf(tq.z, f0.z, fmaf(tq.y, f0.y, fmaf(tq.x, f0.x, f1.x)))); \
            float r = __builtin_amdgcn_rcpf(EXP2(u) + 1.0f); \
            float r2 = __builtin_amdgcn_rcpf(EXP2(fmaf(r, f1.y, f1.z)) + 1.0f); \
            ak = fmaf(r2, f1.w, ak); }
        EVAL(tq0, a0) EVAL(tq1, a1) EVAL(tq2, a2) EVAL(tq3, a3)
        #undef EVAL
    }
    *reinterpret_cast<float4*>(&ACC[chunk][eg]) = make_float4(a0, a1, a2, a3);
    __syncthreads();

    // ---- write phase: waves 0,1 -> rows row0, row0+1 ----
    const int w = t >> 6, lane = t & 63;
    if (w < 2) {
        const int row = row0 + w;
        const int eb = w * 64 + lane;
        float val = swp[0];
        #pragma unroll
        for (int c = 0; c < 8; ++c) val += ACC[c][eb];
        val = fmaxf(val, 0.f);

        float2 exy = EXY[eb];
        float ex = exy.x, ey = exy.y;
        float sx = __shfl(ex, 0), sy = __shfl(ey, 0);   // row center = lane 0
        float att = 0.f;
        #pragma unroll
        for (int j = 0; j < 8; ++j) {
            float qj = fmaf(sy, Wq[8 + j], fmaf(sx, Wq[j], bq[j]));
            float kj = fmaf(ey, Wk[8 + j], fmaf(ex, Wk[j], bk[j]));
            att = fmaf(qj, kj, att);
        }
        att = fabsf(att);

        const int col = idx[E_ + row * K_ + lane];
        float vsum = val, asum = att;
        bool leader = true;
        for (int j = 0; j < 64; ++j) {
            int   bc = __shfl(col, j);
            float bv = __shfl(val, j);
            float ba = __shfl(att, j);
            if (bc == col && j != lane) {
                if (j < lane) leader = false;
                else { vsum += bv; asum += ba; }
            }
        }
        if (leader) {
            size_t p = (size_t)row * N_ + col;
            out[p] = vsum * __expf(-asum * geo[p]) * ang[p];
        }
    }
}

extern "C" void kernel_launch(void* const* d_in, const int* in_sizes, int n_in,
                              void* d_out, int out_size, void* d_ws, size_t ws_size,
                              hipStream_t stream)
{
    const float* coor  = (const float*)d_in[1];
    const int*   idx   = (const int*)d_in[2];
    const float* geo   = (const float*)d_in[3];
    const float* ang   = (const float*)d_in[4];
    const float* W0    = (const float*)d_in[5];
    const float* b0    = (const float*)d_in[6];
    const float* W1    = (const float*)d_in[7];
    const float* b1    = (const float*)d_in[8];
    const float* gamma = (const float*)d_in[9];
    const float* beta  = (const float*)d_in[10];
    const float* W2    = (const float*)d_in[11];
    const float* b2    = (const float*)d_in[12];
    const float* Wq    = (const float*)d_in[13];
    const float* bq    = (const float*)d_in[14];
    const float* Wk    = (const float*)d_in[15];
    const float* bk    = (const float*)d_in[16];

    float* ws     = (float*)d_ws;
    float* swp    = ws;            // 1
    float* W01g   = ws + 256;      // 1280 (5 x 256, TL2E-prescaled)
    float* folded = ws + 2048;     // 2048
    float* part   = ws + 8192;     // 2048 x 512 floats (4 MB)

    // 4 dispatches, no memsets: every ws region is fully written before read.
    prep_kernel<<<1, 256, 0, stream>>>(W0, b0, W1, b1, W2, b2, W01g, swp);
    stats_kernel<<<E_ / 128, 256, 0, stream>>>(coor, W01g, part);
    reduce_fold_kernel<<<256, 256, 0, stream>>>(part, W01g, gamma, beta, W2, folded);
    edge_kernel<<<N_ / 2, 256, 0, stream>>>(coor, idx, folded, swp,
                                            Wq, bq, Wk, bk, geo, ang, (float*)d_out);
}

// Round 8
// 84.501 us; speedup vs baseline: 1.0329x; 1.0329x over previous
//
#include <hip/hip_runtime.h>

#define N_ 4096
#define K_ 64
#define E_ (N_*K_)
#define H_ 256
#define EPS_ 1e-5f
#define L2E_ 1.4426950408889634f   // log2(e)
#define TL2E_ 2.8853900817779268f  // 2*log2(e)

#if __has_builtin(__builtin_amdgcn_exp2f)
#define EXP2(x) __builtin_amdgcn_exp2f(x)
#else
#define EXP2(x) __expf((x) * 0.6931471805599453f)
#endif

// tanh(x) = 1 - 2/(2^(2*log2e*x)+1); inf-safe (exp2(+inf)->inf, rcp(inf)=0)
__device__ __forceinline__ float ftanh(float x) {
    float e = EXP2(x * TL2E_);
    return 1.0f - 2.0f * __builtin_amdgcn_rcpf(e + 1.0f);
}

// One block: W01g[5*256] = TL2E * {W0@W1 (4 rows); b0@W1 + b1};
// swp[0] = sum(W2)+b2; zeroes sums[512] (reduce accumulates atomically).
__global__ __launch_bounds__(256) void prep_kernel(
    const float* __restrict__ W0, const float* __restrict__ b0,
    const float* __restrict__ W1, const float* __restrict__ b1,
    const float* __restrict__ W2, const float* __restrict__ b2,
    float* __restrict__ W01g, float* __restrict__ swp, float* __restrict__ sums)
{
    int c = threadIdx.x;
    float a0 = 0.f, a1 = 0.f, a2 = 0.f, a3 = 0.f, ab = 0.f;
    #pragma unroll 8
    for (int h = 0; h < H_; ++h) {
        float w = W1[h * H_ + c];
        a0 = fmaf(W0[h], w, a0);
        a1 = fmaf(W0[H_ + h], w, a1);
        a2 = fmaf(W0[2 * H_ + h], w, a2);
        a3 = fmaf(W0[3 * H_ + h], w, a3);
        ab = fmaf(b0[h], w, ab);
    }
    W01g[c]          = TL2E_ * a0;
    W01g[H_ + c]     = TL2E_ * a1;
    W01g[2 * H_ + c] = TL2E_ * a2;
    W01g[3 * H_ + c] = TL2E_ * a3;
    W01g[4 * H_ + c] = TL2E_ * (ab + b1[c]);
    sums[c] = 0.f;
    sums[H_ + c] = 0.f;

    __shared__ float red[256];
    red[c] = W2[c];
    __syncthreads();
    for (int s = 128; s > 0; s >>= 1) {
        if (c < s) red[c] += red[c + s];
        __syncthreads();
    }
    if (c == 0) swp[0] = red[0] + b2[0];
}

// Per-column partial sums of r = 1/(2^u+1) and r^2 over a 128-edge tile.
// Coalesced part[block][512] writes, no atomics.
__global__ __launch_bounds__(256, 8) void stats_kernel(
    const float* __restrict__ coor, const float* __restrict__ W01g,
    float* __restrict__ part)
{
    const int c = threadIdx.x;
    const float w0 = W01g[c],          w1 = W01g[H_ + c];
    const float w2 = W01g[2 * H_ + c], w3 = W01g[3 * H_ + c];
    const float bb = W01g[4 * H_ + c];
    __shared__ float4 T[128];
    const int e0 = blockIdx.x * 128;
    if (c < 128) {
        float4 v = reinterpret_cast<const float4*>(coor)[e0 + c];
        T[c] = make_float4(ftanh(v.x), ftanh(v.y), ftanh(v.z), ftanh(v.w));
    }
    __syncthreads();
    float sr = 0.f, sr2 = 0.f;
    #pragma unroll 8
    for (int i = 0; i < 128; ++i) {
        float4 t = T[i];
        float u = fmaf(t.w, w3, fmaf(t.z, w2, fmaf(t.y, w1, fmaf(t.x, w0, bb))));
        float r = __builtin_amdgcn_rcpf(EXP2(u) + 1.0f);
        sr += r;
        sr2 = fmaf(r, r, sr2);
    }
    part[blockIdx.x * 512 + c] = sr;
    part[blockIdx.x * 512 + 256 + c] = sr2;
}

// Row-wise coalesced reduce (R5 form): 32 blocks x 512 threads, thread t sums
// part[b*512+t] over its 64 blocks (consecutive t = consecutive addresses),
// one atomicAdd per thread (32-deep chains).
__global__ __launch_bounds__(512) void reduce_kernel(
    const float* __restrict__ part, float* __restrict__ sums)
{
    int t = threadIdx.x;
    int b0 = blockIdx.x * 64;
    float local = 0.f;
    #pragma unroll 8
    for (int b = b0; b < b0 + 64; ++b) local += part[b * 512 + t];
    atomicAdd(&sums[t], local);
}

// Fused edge kernel, block = 2 rows (128 edges).
// Stage: BN-fold col t from sums -> FS (no folded round-trip); tanh quads; col.
// barrier 1 (no pending mass stores -> cheap drain)
// Then: issue zero-fill + geo/ang prefetch (drain under compute), compute
// 4 edges x 32 cols/thread, barrier 2 (stores/loads already landed), write.
__global__ __launch_bounds__(256, 8) void edge_kernel(
    const float* __restrict__ coor, const int* __restrict__ idx,
    const float* __restrict__ sums, const float* __restrict__ W01g,
    const float* __restrict__ gamma, const float* __restrict__ beta,
    const float* __restrict__ W2, const float* __restrict__ swp,
    const float* __restrict__ Wq, const float* __restrict__ bq,
    const float* __restrict__ Wk, const float* __restrict__ bk,
    const float* __restrict__ geo, const float* __restrict__ ang,
    float* __restrict__ out)
{
    __shared__ float4 FS[2 * H_];   // folded per-column records
    __shared__ float4 TS[128];      // per-edge tanh quads
    __shared__ float2 EXY[128];     // per-edge (ex,ey)
    __shared__ float  ACC[8][128];  // chunk x edge partial accs

    const int t = threadIdx.x;
    const int row0 = blockIdx.x * 2;

    // ---- stage: BN-fold this thread's column directly into FS ----
    {
        const float inv = 1.0f / (float)E_;
        float sp = sums[t] * inv;
        float sq = sums[H_ + t] * inv;
        float mu = 1.0f - 2.0f * sp;            // mean of h = 1-2r
        float var = 4.0f * fmaf(-sp, sp, sq);
        float a  = gamma[t] * rsqrtf(var + EPS_);
        float bf = fmaf(-mu, a, beta[t]);
        FS[2 * t]     = make_float4(W01g[t], W01g[H_ + t], W01g[2 * H_ + t], W01g[3 * H_ + t]);
        FS[2 * t + 1] = make_float4(W01g[4 * H_ + t], -4.0f * L2E_ * a,
                                    TL2E_ * (a + bf), -2.0f * W2[t]);
    }
    int col = 0;
    if (t < 128) {
        float4 ce = reinterpret_cast<const float4*>(coor)[row0 * K_ + t];
        TS[t] = make_float4(ftanh(ce.x), ftanh(ce.y), ftanh(ce.z), ftanh(ce.w));
        EXY[t] = make_float2(ce.x + ce.z, ce.y + ce.w);
        col = idx[E_ + row0 * K_ + t];          // coalesced row segment
    }
    __syncthreads();   // barrier 1: LDS ready; only small loads to drain

    // ---- issue zero-fill (drains under compute, collected at barrier 2) ----
    {
        float4 z = make_float4(0.f, 0.f, 0.f, 0.f);
        float4* orow = reinterpret_cast<float4*>(out + (size_t)row0 * N_);
        #pragma unroll
        for (int i = 0; i < 8; ++i) orow[i * 256 + t] = z;
    }
    // ---- geo/ang prefetch (scattered; latency hidden by compute) ----
    size_t p = 0;
    float g = 0.f, an = 0.f;
    if (t < 128) {
        p = (size_t)(row0 + (t >> 6)) * N_ + col;
        g = geo[p];
        an = ang[p];
    }

    // ---- compute: 4 edges x 32 columns per thread ----
    const int eg = (t & 31) * 4;
    const int chunk = t >> 5;
    const float4 tq0 = TS[eg], tq1 = TS[eg + 1], tq2 = TS[eg + 2], tq3 = TS[eg + 3];
    const float4* Fp = &FS[chunk * 64];
    float a0 = 0.f, a1 = 0.f, a2 = 0.f, a3 = 0.f;
    #pragma unroll 4
    for (int i = 0; i < 32; ++i) {
        float4 f0 = Fp[2 * i];
        float4 f1 = Fp[2 * i + 1];
        #define EVAL(tq, ak) { \
            float u = fmaf(tq.w, f0.w, fmaf(tq.z, f0.z, fmaf(tq.y, f0.y, fmaf(tq.x, f0.x, f1.x)))); \
            float r = __builtin_amdgcn_rcpf(EXP2(u) + 1.0f); \
            float r2 = __builtin_amdgcn_rcpf(EXP2(fmaf(r, f1.y, f1.z)) + 1.0f); \
            ak = fmaf(r2, f1.w, ak); }
        EVAL(tq0, a0) EVAL(tq1, a1) EVAL(tq2, a2) EVAL(tq3, a3)
        #undef EVAL
    }
    *reinterpret_cast<float4*>(&ACC[chunk][eg]) = make_float4(a0, a1, a2, a3);
    __syncthreads();   // barrier 2: ACC ready; zero stores + g/an drained here

    // ---- write phase: waves 0,1 -> rows row0, row0+1 ----
    const int w = t >> 6, lane = t & 63;
    if (w < 2) {
        const int eb = t;   // = w*64+lane
        float val = swp[0];
        #pragma unroll
        for (int c = 0; c < 8; ++c) val += ACC[c][eb];
        val = fmaxf(val, 0.f);

        float2 exy = EXY[eb];
        float ex = exy.x, ey = exy.y;
        float sx = __shfl(ex, 0), sy = __shfl(ey, 0);   // row center = lane 0
        float att = 0.f;
        #pragma unroll
        for (int j = 0; j < 8; ++j) {
            float qj = fmaf(sy, Wq[8 + j], fmaf(sx, Wq[j], bq[j]));
            float kj = fmaf(ey, Wk[8 + j], fmaf(ex, Wk[j], bk[j]));
            att = fmaf(qj, kj, att);
        }
        att = fabsf(att);

        float vsum = val, asum = att;
        bool leader = true;
        for (int j = 0; j < 64; ++j) {
            int   bc = __shfl(col, j);
            float bv = __shfl(val, j);
            float ba = __shfl(att, j);
            if (bc == col && j != lane) {
                if (j < lane) leader = false;
                else { vsum += bv; asum += ba; }
            }
        }
        if (leader) {
            out[p] = vsum * __expf(-asum * g) * an;
        }
    }
}

extern "C" void kernel_launch(void* const* d_in, const int* in_sizes, int n_in,
                              void* d_out, int out_size, void* d_ws, size_t ws_size,
                              hipStream_t stream)
{
    const float* coor  = (const float*)d_in[1];
    const int*   idx   = (const int*)d_in[2];
    const float* geo   = (const float*)d_in[3];
    const float* ang   = (const float*)d_in[4];
    const float* W0    = (const float*)d_in[5];
    const float* b0    = (const float*)d_in[6];
    const float* W1    = (const float*)d_in[7];
    const float* b1    = (const float*)d_in[8];
    const float* gamma = (const float*)d_in[9];
    const float* beta  = (const float*)d_in[10];
    const float* W2    = (const float*)d_in[11];
    const float* b2    = (const float*)d_in[12];
    const float* Wq    = (const float*)d_in[13];
    const float* bq    = (const float*)d_in[14];
    const float* Wk    = (const float*)d_in[15];
    const float* bk    = (const float*)d_in[16];

    float* ws   = (float*)d_ws;
    float* swp  = ws;              // 1
    float* sums = ws + 256;        // 512 (re-zeroed by prep each call)
    float* W01g = ws + 1024;       // 1280 (5 x 256, TL2E-prescaled)
    float* part = ws + 4096;       // 2048 x 512 floats (4 MB)

    prep_kernel<<<1, 256, 0, stream>>>(W0, b0, W1, b1, W2, b2, W01g, swp, sums);
    stats_kernel<<<E_ / 128, 256, 0, stream>>>(coor, W01g, part);
    reduce_kernel<<<32, 512, 0, stream>>>(part, sums);
    edge_kernel<<<N_ / 2, 256, 0, stream>>>(coor, idx, sums, W01g, gamma, beta,
                                            W2, swp, Wq, bq, Wk, bk, geo, ang,
                                            (float*)d_out);
}